// Round 12
// baseline (347.050 us; speedup 1.0000x reference)
//
#include <hip/hip_runtime.h>
#include <hip/hip_bf16.h>

#define N_NODES 30000
#define N_EDGE  60000
#define T_TOK   90000
#define M_MSG   390000
#define DD      256
#define HH      8
#define AS      260   // bf16 LDS tile stride (520 B rows: conflict-free b64 frag reads)
#define FUSED_BLKS 1407  // ceil(90000/64)
#define HIST_BLKS  762   // ceil(390000/512)

typedef unsigned short u16;
typedef unsigned int   u32;
typedef short s16x8 __attribute__((ext_vector_type(8)));
typedef float f32x4 __attribute__((ext_vector_type(4)));

// ---------- workspace layout (bytes) ----------
constexpr size_t WS_V     = 0;                                   // bf16 [T][256]
constexpr size_t WS_ALR   = WS_V    + (size_t)T_TOK * DD * 2;    // f32  [T][8]
constexpr size_t WS_CNT   = WS_ALR  + (size_t)T_TOK * HH * 4;    // int  [N]
constexpr size_t WS_OFF   = WS_CNT  + (size_t)N_NODES * 4;       // int  [N+1]
constexpr size_t WS_CUR   = WS_OFF  + (size_t)(N_NODES + 1) * 4; // int  [N]
constexpr size_t WS_MSRC  = WS_CUR  + (size_t)N_NODES * 4;       // int  [M]
constexpr size_t WS_SMALL = ((WS_MSRC + (size_t)M_MSG * 4) + 255) & ~(size_t)255;

struct Small {
  u16 wts[16][256];     // folded score weights bf16, FRAGMENT-LINEAR
  float b0[8], b1f[8];
  float q[2][256];      // q0/q1 vectors (post q-MLP)
  float pe_c1[11][256]; // pe1[order] @ m1_w1[256:512,:]
  float pc2[2][256];    // pe2[s] @ m2_w1[256:512,:]
  float att0_vec[256];
  float att0_upd[256];
};
constexpr size_t WS_WTS  = (WS_SMALL + sizeof(Small) + 255) & ~(size_t)255;
constexpr size_t WS_PART = WS_WTS  + 7 * 65536 * 2;              // f32 [FUSED_BLKS][256]
constexpr size_t WS_PDEN = WS_PART + (size_t)FUSED_BLKS * 256 * 4; // f32 [FUSED_BLKS][8]
constexpr size_t WS_PMAX = WS_PDEN + (size_t)FUSED_BLKS * 8 * 4;   // f32 [FUSED_BLKS][8]

__device__ __forceinline__ float bf2f(u16 a){ return __uint_as_float(((u32)a) << 16); }
// gfx950 v_cvt_pk_bf16_f32: packs 2 f32 -> 2 bf16 (RNE) in one instruction (T12 recipe)
__device__ __forceinline__ u32 pkbf(float lo, float hi){
  u32 r;
  asm("v_cvt_pk_bf16_f32 %0, %1, %2" : "=v"(r) : "v"(lo), "v"(hi));
  return r;
}
__device__ __forceinline__ u16 f2bf(float f){ return (u16)pkbf(f, f); }
__device__ __forceinline__ float wredsum(float x){
  #pragma unroll
  for (int s = 32; s > 0; s >>= 1) x += __shfl_xor(x, s, 64);
  return x;
}
__device__ __forceinline__ float wredmax(float x){
  #pragma unroll
  for (int s = 32; s > 0; s >>= 1) x = fmaxf(x, __shfl_xor(x, s, 64));
  return x;
}

union U8 { s16x8 v; uint2 u2[2]; uint4 u4; };

// ---------- MFMA 64-row tile GEMM (8 waves, 512 thr): wave w -> cols w*32..w*32+31 ----------
template<bool SC>
__device__ __forceinline__ void mfma_tile64(const u16* sa, const u16* __restrict__ WT,
                                            const u16* __restrict__ wts, int tid,
                                            f32x4 fr[4][2], f32x4* fs)
{
  const int lane = tid & 63, w = tid >> 6;
  const int l15 = lane & 15, g = lane >> 4;
  const int slab = w >> 1, nt0 = (w & 1) * 2;
  #pragma unroll
  for (int m = 0; m < 4; m++)
    #pragma unroll
    for (int n = 0; n < 2; n++) fr[m][n] = (f32x4){0.f, 0.f, 0.f, 0.f};
  const u16* ap = sa + l15 * AS + 4 * g;
  const u16* bp = WT + (size_t)slab * 16384 + lane * 8;
  const bool do_s = SC && (w == 0);
  #pragma unroll 4
  for (int c = 0; c < 8; c++){
    const int k0 = c * 32;
    U8 a[4];
    #pragma unroll
    for (int m = 0; m < 4; m++){
      a[m].u2[0] = *(const uint2*)(ap + m * 16 * AS + k0);
      a[m].u2[1] = *(const uint2*)(ap + m * 16 * AS + k0 + 16);
    }
    U8 b[2];
    #pragma unroll
    for (int n = 0; n < 2; n++)
      b[n].u4 = *(const uint4*)(bp + (c * 4 + nt0 + n) * 512);
    #pragma unroll
    for (int n = 0; n < 2; n++)
      #pragma unroll
      for (int m = 0; m < 4; m++)
        fr[m][n] = __builtin_amdgcn_mfma_f32_16x16x32_bf16(a[m].v, b[n].v, fr[m][n], 0, 0, 0);
    if (do_s){
      U8 bs;
      bs.u4 = *(const uint4*)(wts + c * 512 + lane * 8);
      #pragma unroll
      for (int m = 0; m < 4; m++)
        fs[m] = __builtin_amdgcn_mfma_f32_16x16x32_bf16(a[m].v, bs.v, fs[m], 0, 0, 0);
    }
  }
}

// ---------- K0a: q MLP (1 block, 512 thr) -> sm->q, b0/b1f; zero cnt ----------
__global__ void k_preq(const float* __restrict__ qw1, const float* __restrict__ qb1,
                       const float* __restrict__ qw2, const float* __restrict__ qb2,
                       const float* __restrict__ kb, Small* sm, int* cnt)
{
  __shared__ float s_qin[2][128];
  __shared__ float s_h1[2][256];
  __shared__ float s_q[2][256];
  int tid = threadIdx.x;
  int p = tid >> 8, col = tid & 255;
  for (int i = tid; i < N_NODES; i += 512) cnt[i] = 0;
  if (tid < 128){
    int i = tid >> 1;
    float dv = expf((float)(2 * i) * (-9.210340371976184f / 128.f));
    if (tid & 1){ s_qin[0][tid] = 1.f; s_qin[1][tid] = cosf(dv); }
    else        { s_qin[0][tid] = 0.f; s_qin[1][tid] = sinf(dv); }
  }
  __syncthreads();
  {
    float acc = qb1[col];
    for (int d = 0; d < 128; d++) acc = fmaf(s_qin[p][d], qw1[d * 256 + col], acc);
    s_h1[p][col] = fmaxf(acc, 0.f);
  }
  __syncthreads();
  {
    float acc = qb2[col];
    for (int k = 0; k < 256; k++) acc = fmaf(s_h1[p][k], qw2[k * 256 + col], acc);
    s_q[p][col] = acc;
    sm->q[p][col] = acc;
  }
  __syncthreads();
  if (tid < 8){
    float b0 = 0.f, b1 = 0.f;
    for (int i = 0; i < 32; i++){
      b0 = fmaf(kb[tid * 32 + i],       s_q[0][tid * 32 + i], b0);
      b1 = fmaf(kb[256 + tid * 32 + i], s_q[1][tid * 32 + i], b1);
    }
    sm->b0[tid] = b0; sm->b1f[tid] = b1;
  }
}

// ---------- K0b: merged precompute — roles 0..19 = kw-fold/PE tables, 20..243 = wconv ----------
__global__ void k_prep(const float* __restrict__ kw, const float* __restrict__ m1w1,
                       const float* __restrict__ m2w1, Small* sm,
                       const float* __restrict__ s0, const float* __restrict__ s1,
                       const float* __restrict__ s2, const float* __restrict__ s3,
                       const float* __restrict__ s4, const float* __restrict__ s5,
                       const float* __restrict__ s6, u16* __restrict__ dst)
{
  int role = blockIdx.x, tid = threadIdx.x;
  if (role < 8){
    int d = role * 32 + (tid >> 3), h = tid & 7;
    float a0 = 0.f, a1 = 0.f;
    #pragma unroll
    for (int i = 0; i < 32; i++){
      a0 = fmaf(kw[d * 512 + h * 32 + i],       sm->q[0][h * 32 + i], a0);
      a1 = fmaf(kw[d * 512 + 256 + h * 32 + i], sm->q[1][h * 32 + i], a1);
    }
    int c = d >> 5, kk = d & 31;
    int g = (kk & 15) >> 2;
    int j = (kk & 3) + ((kk & 16) ? 4 : 0);
    u16* wf = &sm->wts[0][0];
    wf[(c * 64 + g * 16 + h) * 8 + j]     = f2bf(a0);
    wf[(c * 64 + g * 16 + 8 + h) * 8 + j] = f2bf(a1);
  } else if (role < 19){
    __shared__ float s_pe[256];
    int o = role - 8;
    {
      int i = tid >> 1;
      float dv = expf((float)(2 * i) * (-9.210340371976184f / 256.f));
      float ph = (float)o * dv;
      s_pe[tid] = (tid & 1) ? cosf(ph) : sinf(ph);
    }
    __syncthreads();
    float acc = 0.f;
    for (int d = 0; d < 256; d++) acc = fmaf(s_pe[d], m1w1[(256 + d) * 256 + tid], acc);
    sm->pe_c1[o][tid] = acc;
  } else if (role == 19){
    __shared__ float p0[256], p1[256];
    {
      int i = tid >> 1;
      float dv = expf((float)(2 * i) * (-9.210340371976184f / 256.f));
      p0[tid] = (tid & 1) ? 1.f : 0.f;
      p1[tid] = (tid & 1) ? cosf(dv) : sinf(dv);
    }
    __syncthreads();
    float a0 = 0.f, a1 = 0.f;
    for (int d = 0; d < 256; d++){
      float w = m2w1[(256 + d) * 256 + tid];
      a0 = fmaf(p0[d], w, a0);
      a1 = fmaf(p1[d], w, a1);
    }
    sm->pc2[0][tid] = a0; sm->pc2[1][tid] = a1;
  } else {
    int b = role - 20;             // 224 wconv tiles: 7 mats x 4 slabs x 8 chunks
    int mat = b >> 5, rem = b & 31;
    int slab = rem >> 3, c = rem & 7;
    const float* S;
    switch (mat){ case 0: S = s0; break; case 1: S = s1; break; case 2: S = s2; break;
                  case 3: S = s3; break; case 4: S = s4; break; case 5: S = s5; break;
                  default: S = s6; }
    int nt = tid >> 6, lane = tid & 63;
    int l15 = lane & 15, g = lane >> 4;
    int n = slab * 64 + nt * 16 + l15;
    u16 tmp[8];
    #pragma unroll
    for (int j = 0; j < 8; j++){
      int k = c * 32 + g * 4 + (j & 3) + ((j >= 4) ? 16 : 0);
      tmp[j] = f2bf(S[(size_t)k * 256 + n]);
    }
    uint4 o;
    o.x = (u32)tmp[0] | ((u32)tmp[1] << 16);
    o.y = (u32)tmp[2] | ((u32)tmp[3] << 16);
    o.z = (u32)tmp[4] | ((u32)tmp[5] << 16);
    o.w = (u32)tmp[6] | ((u32)tmp[7] << 16);
    *(uint4*)(dst + (size_t)mat * 65536 + (size_t)((((slab * 8 + c) * 4 + nt) * 64 + lane) * 8)) = o;
  }
}

// ---------- K1: FUSED phase-1 MLP + V proj + scores + att0 block-partials + hist roles ----------
__global__ __launch_bounds__(512, 4) void k_fused1(
    const float* __restrict__ x_v, const float* __restrict__ x_e,
    const int* __restrict__ edge_orders,
    const u16* __restrict__ WTa, const u16* __restrict__ WTb, const u16* __restrict__ WTv,
    const float* __restrict__ b1, const float* __restrict__ b2,
    const float* __restrict__ n1g, const float* __restrict__ n1b,
    const float* __restrict__ vb,
    const Small* __restrict__ sm,
    u16* __restrict__ v, float* __restrict__ alr,
    float* __restrict__ part, float* __restrict__ pden, float* __restrict__ pmax,
    const int* __restrict__ tgt, int* __restrict__ cnt)
{
  if (blockIdx.x >= FUSED_BLKS){
    int m = (blockIdx.x - FUSED_BLKS) * 512 + threadIdx.x;
    if (m < M_MSG) atomicAdd(&cnt[tgt[m]], 1);
    return;
  }
  __shared__ u16 s_a[64 * AS];   // 33.3 KB
  __shared__ int s_ord[64];
  __shared__ float s_l[64][8];   // logit tile (fake rows = -1e30)
  __shared__ float s_e[8][64];   // per-head exp weights
  __shared__ float s_p2[512];
  const int tid = threadIdx.x;
  const int t0  = blockIdx.x * 64;
  const int w = tid >> 6, lane = tid & 63;
  const int l15 = lane & 15, g = lane >> 4;
  const int cb = w * 32;

  // ---- load x + LN -> s_a; residual x kept packed bf16 in regs (fully unrolled: rule #20) ----
  uint2 xp[8];
  {
    float4 gg = *(const float4*)(n1g + lane * 4);
    float4 bb = *(const float4*)(n1b + lane * 4);
    #pragma unroll
    for (int i = 0; i < 8; i++){
      int r = w * 8 + i;
      int t = t0 + r;
      float4 xv = make_float4(0.f, 0.f, 0.f, 0.f);
      if (t < T_TOK){
        const float* p = (t < N_EDGE) ? (x_e + (size_t)t * DD) : (x_v + (size_t)(t - N_EDGE) * DD);
        xv = *(const float4*)(p + lane * 4);
      }
      xp[i].x = pkbf(xv.x, xv.y);
      xp[i].y = pkbf(xv.z, xv.w);
      float s  = xv.x + xv.y + xv.z + xv.w;
      float ss = fmaf(xv.x, xv.x, fmaf(xv.y, xv.y, fmaf(xv.z, xv.z, xv.w * xv.w)));
      s = wredsum(s); ss = wredsum(ss);
      float mu  = s * (1.f / 256.f);
      float var = fmaf(-mu, mu, ss * (1.f / 256.f));
      float rs  = rsqrtf(var + 1e-5f);
      uint2 p2;
      p2.x = pkbf(fmaf((xv.x - mu) * rs, gg.x, bb.x), fmaf((xv.y - mu) * rs, gg.y, bb.y));
      p2.y = pkbf(fmaf((xv.z - mu) * rs, gg.z, bb.z), fmaf((xv.w - mu) * rs, gg.w, bb.w));
      *(uint2*)(s_a + r * AS + lane * 4) = p2;
    }
  }
  if (tid < 64){
    int t = t0 + tid;
    s_ord[tid] = (t < N_EDGE) ? edge_orders[t] : 1;
  }
  __syncthreads();

  f32x4 fr[4][2];
  // ---- GEMM1: h1 = relu(LN(x) @ m1w1 + b1 + pe) ----
  mfma_tile64<false>(s_a, WTa, nullptr, tid, fr, nullptr);
  __syncthreads();
  {
    float b1c[2];
    #pragma unroll
    for (int n = 0; n < 2; n++) b1c[n] = b1[cb + n * 16 + l15];
    #pragma unroll
    for (int m = 0; m < 4; m++){
      #pragma unroll
      for (int r = 0; r < 4; r++){
        int row = m * 16 + 4 * g + r;
        const float* per = &sm->pe_c1[s_ord[row]][0];
        #pragma unroll
        for (int n = 0; n < 2; n++){
          int col = cb + n * 16 + l15;
          s_a[row * AS + col] = f2bf(fmaxf(fr[m][n][r] + b1c[n] + per[col], 0.f));
        }
      }
    }
  }
  __syncthreads();
  // ---- GEMM2: mlp = h1 @ m1w2 + b2 -> back into s_a ----
  mfma_tile64<false>(s_a, WTb, nullptr, tid, fr, nullptr);
  __syncthreads();
  {
    float b2c[2];
    #pragma unroll
    for (int n = 0; n < 2; n++) b2c[n] = b2[cb + n * 16 + l15];
    #pragma unroll
    for (int m = 0; m < 4; m++)
      #pragma unroll
      for (int n = 0; n < 2; n++){
        int col = cb + n * 16 + l15;
        #pragma unroll
        for (int r = 0; r < 4; r++){
          int row = m * 16 + 4 * g + r;
          s_a[row * AS + col] = f2bf(fr[m][n][r] + b2c[n]);
        }
      }
  }
  __syncthreads();
  // ---- tok = bf16(mlp + x): in-place RMW ----
  #pragma unroll
  for (int i = 0; i < 8; i++){
    int r = w * 8 + i;
    uint2 q = *(const uint2*)(s_a + r * AS + lane * 4);
    uint2 xq = xp[i];
    uint2 o;
    o.x = pkbf(bf2f((u16)(q.x & 0xffff)) + bf2f((u16)(xq.x & 0xffff)),
               bf2f((u16)(q.x >> 16))    + bf2f((u16)(xq.x >> 16)));
    o.y = pkbf(bf2f((u16)(q.y & 0xffff)) + bf2f((u16)(xq.y & 0xffff)),
               bf2f((u16)(q.y >> 16))    + bf2f((u16)(xq.y >> 16)));
    *(uint2*)(s_a + r * AS + lane * 4) = o;
  }
  __syncthreads();
  // ---- GEMM3: v = tok @ v_w + vb (+ score GEMM on wave 0) ----
  f32x4 fs[4];
  #pragma unroll
  for (int m = 0; m < 4; m++) fs[m] = (f32x4){0.f, 0.f, 0.f, 0.f};
  mfma_tile64<true>(s_a, WTv, &sm->wts[0][0], tid, fr, fs);
  __syncthreads();
  {
    float vbc[2];
    #pragma unroll
    for (int n = 0; n < 2; n++) vbc[n] = vb[cb + n * 16 + l15];
    #pragma unroll
    for (int m = 0; m < 4; m++)
      #pragma unroll
      for (int n = 0; n < 2; n++){
        int col = cb + n * 16 + l15;
        #pragma unroll
        for (int r = 0; r < 4; r++){
          int row = m * 16 + 4 * g + r;
          s_a[row * AS + col] = f2bf(fr[m][n][r] + vbc[n]);
        }
      }
  }
  if (w == 0){
    #pragma unroll
    for (int m = 0; m < 4; m++)
      #pragma unroll
      for (int r = 0; r < 4; r++){
        int row = m * 16 + 4 * g + r;
        int t = t0 + row;
        int sc = l15;
        if (sc < 8){
          float lv = (t < T_TOK) ? (fs[m][r] + sm->b0[sc]) * 0.17677669529663687f : -1e30f;
          s_l[row][sc] = lv;
        } else if (t < T_TOK){
          float a_ = fs[m][r] + sm->b1f[sc - 8];
          alr[(size_t)t * 8 + sc - 8] = (a_ > 0.f) ? a_ : 0.2f * a_;
        }
      }
  }
  __syncthreads();   // s_a = v-tile visible; s_l visible
  // ---- att0 block-partials: wave w = head w computes per-row exp weights ----
  {
    float lv = s_l[lane][w];
    float mxb = wredmax(lv);
    float e = __expf(lv - mxb);
    float den = wredsum(e);
    s_e[w][lane] = e;
    if (lane == 0){
      pden[(size_t)blockIdx.x * 8 + w] = den;
      pmax[(size_t)blockIdx.x * 8 + w] = mxb;
    }
  }
  __syncthreads();
  // ---- weighted V-sum: 2 threads/col x 32 rows each ----
  {
    int col = tid & 255, half = tid >> 8;
    int h = col >> 5;
    float acc = 0.f;
    #pragma unroll 8
    for (int r2 = half * 32; r2 < half * 32 + 32; r2++)
      acc = fmaf(s_e[h][r2], bf2f(s_a[r2 * AS + col]), acc);
    s_p2[tid] = acc;
  }
  __syncthreads();
  if (tid < 256) part[(size_t)blockIdx.x * 256 + tid] = s_p2[tid] + s_p2[tid + 256];
  // ---- stage v -> global (coalesced uint4) ----
  #pragma unroll
  for (int i = 0; i < 4; i++){
    int ch = i * 512 + tid;
    int r = ch >> 5, c8 = (ch & 31) * 8;
    int t = t0 + r;
    if (t < T_TOK){
      uint2 q0 = *(const uint2*)(s_a + r * AS + c8);
      uint2 q1 = *(const uint2*)(s_a + r * AS + c8 + 4);
      *(uint4*)(v + (size_t)t * DD + c8) = make_uint4(q0.x, q0.y, q1.x, q1.y);
    }
  }
}

// ---------- K2: block 0 = CSR scan; block 1 = att0 combine + epilogue MLP ----------
__global__ __launch_bounds__(1024) void k_scanbc(
    const int* __restrict__ cnt, int* __restrict__ off, int* __restrict__ cur,
    const float* __restrict__ part, const float* __restrict__ pden, const float* __restrict__ pmax,
    const float* __restrict__ m2w1, const float* __restrict__ m2b1,
    const float* __restrict__ m2w2, const float* __restrict__ m2b2,
    const float* __restrict__ n2g, const float* __restrict__ n2b,
    Small* sm)
{
  int tid = threadIdx.x;
  if (blockIdx.x == 0){
    // ---- exclusive scan of cnt -> off, cur ----
    __shared__ int s_s[1024];
    int base = tid * 30;
    int s = 0;
    if (tid < 1000){
      for (int i = 0; i < 30; i++) s += cnt[base + i];
    }
    s_s[tid] = s;
    __syncthreads();
    for (int ofs = 1; ofs < 1024; ofs <<= 1){
      int v_ = (tid >= ofs) ? s_s[tid - ofs] : 0;
      __syncthreads();
      s_s[tid] += v_;
      __syncthreads();
    }
    if (tid < 1000){
      int run = (tid == 0) ? 0 : s_s[tid - 1];
      for (int i = 0; i < 30; i++){
        int c = cnt[base + i];
        off[base + i] = run; cur[base + i] = run;
        run += c;
      }
    }
    if (tid == 0) off[N_NODES] = M_MSG;
    return;
  }
  // ---- att0 combine: gmax, denom, rescaled column sums, LN + m2 MLP ----
  __shared__ float s_acc[4][256];
  __shared__ float s_red[256];
  __shared__ float s_g[8], s_gi[8];
  __shared__ float s_ln[256], s_h[256], s_r2[8];
  // gmax per head
  if (tid < 256){
    int h = tid & 7, bi = tid >> 3;
    float m = -1e30f;
    for (int b = bi; b < FUSED_BLKS; b += 32) m = fmaxf(m, pmax[(size_t)b * 8 + h]);
    s_red[tid] = m;
  }
  __syncthreads();
  for (int s = 128; s >= 8; s >>= 1){ if (tid < s) s_red[tid] = fmaxf(s_red[tid], s_red[tid + s]); __syncthreads(); }
  if (tid < 8) s_g[tid] = s_red[tid];
  __syncthreads();
  // denom per head (rescaled)
  if (tid < 256){
    int h = tid & 7, bi = tid >> 3;
    float gm = s_g[h];
    float s = 0.f;
    for (int b = bi; b < FUSED_BLKS; b += 32)
      s += pden[(size_t)b * 8 + h] * __expf(pmax[(size_t)b * 8 + h] - gm);
    s_red[tid] = s;
  }
  __syncthreads();
  for (int s = 128; s >= 8; s >>= 1){ if (tid < s) s_red[tid] += s_red[tid + s]; __syncthreads(); }
  if (tid < 8) s_gi[tid] = 1.f / s_red[tid];
  __syncthreads();
  // rescaled column sums over FUSED_BLKS partials (4 groups)
  {
    int col = tid & 255, bg = tid >> 8;
    int h = col >> 5;
    float gm = s_g[h];
    float s = 0.f;
    for (int b = bg; b < FUSED_BLKS; b += 4)
      s += part[(size_t)b * 256 + col] * __expf(pmax[(size_t)b * 8 + h] - gm);
    s_acc[bg][col] = s;
  }
  __syncthreads();
  float x = 0.f;
  if (tid < 256){
    x = (s_acc[0][tid] + s_acc[1][tid] + s_acc[2][tid] + s_acc[3][tid]) * s_gi[tid >> 5];
    sm->att0_vec[tid] = x;
  }
  float s1 = 0.f, s2 = 0.f;
  if (tid < 256){ s1 = wredsum(x); s2 = wredsum(x * x); }
  if (tid < 256 && (tid & 63) == 0){ s_r2[tid >> 6] = s1; s_r2[4 + (tid >> 6)] = s2; }
  __syncthreads();
  if (tid < 256){
    float tot  = s_r2[0] + s_r2[1] + s_r2[2] + s_r2[3];
    float tot2 = s_r2[4] + s_r2[5] + s_r2[6] + s_r2[7];
    float mu  = tot * (1.f / 256.f);
    float var = tot2 * (1.f / 256.f) - mu * mu;
    float rs  = rsqrtf(var + 1e-5f);
    s_ln[tid] = (x - mu) * rs * n2g[tid] + n2b[tid];
  }
  __syncthreads();
  {
    int col = tid & 255, kg = tid >> 8;
    float acc = 0.f;
    for (int k = kg * 64; k < (kg + 1) * 64; k++) acc = fmaf(s_ln[k], m2w1[k * 256 + col], acc);
    s_acc[kg][col] = acc;
  }
  __syncthreads();
  if (tid < 256){
    float acc = s_acc[0][tid] + s_acc[1][tid] + s_acc[2][tid] + s_acc[3][tid]
              + m2b1[tid] + sm->pc2[0][tid];
    s_h[tid] = fmaxf(acc, 0.f);
  }
  __syncthreads();
  {
    int col = tid & 255, kg = tid >> 8;
    float acc = 0.f;
    for (int k = kg * 64; k < (kg + 1) * 64; k++) acc = fmaf(s_h[k], m2w2[k * 256 + col], acc);
    s_acc[kg][col] = acc;
  }
  __syncthreads();
  if (tid < 256){
    sm->att0_upd[tid] = x + s_acc[0][tid] + s_acc[1][tid] + s_acc[2][tid] + s_acc[3][tid] + m2b2[tid];
  }
}

// ---------- CSR scatter ----------
__global__ void k_scatter(const int* __restrict__ src, const int* __restrict__ tgt,
                          int* __restrict__ cur, int* __restrict__ msrc){
  int m = blockIdx.x * 256 + threadIdx.x;
  if (m < M_MSG){
    int slot = atomicAdd(&cur[tgt[m]], 1);
    msrc[slot] = src[m];
  }
}

// ---------- segment softmax + weighted gather (att1): one wave per node, 2-way ILP ----------
__global__ __launch_bounds__(256) void k_att1(
    const int* __restrict__ off, const int* __restrict__ msrc,
    const float* __restrict__ alr, const u16* __restrict__ v,
    float* att1)
{
  int tid = threadIdx.x;
  int n = blockIdx.x * 4 + (tid >> 6);
  if (n >= N_NODES) return;
  int l = tid & 63;
  int h = l >> 3;
  int beg = off[n], end = off[n + 1];
  float mxa = -1e30f, mxb = -1e30f;
  int i = beg;
  for (; i + 1 < end; i += 2){
    mxa = fmaxf(mxa, alr[(size_t)msrc[i] * 8 + h]);
    mxb = fmaxf(mxb, alr[(size_t)msrc[i + 1] * 8 + h]);
  }
  if (i < end) mxa = fmaxf(mxa, alr[(size_t)msrc[i] * 8 + h]);
  float mx = fmaxf(mxa, mxb);
  float den0 = 0.f, den1 = 0.f;
  float a0 = 0.f, a1 = 0.f, a2 = 0.f, a3 = 0.f;
  float c0 = 0.f, c1 = 0.f, c2 = 0.f, c3 = 0.f;
  i = beg;
  for (; i + 1 < end; i += 2){
    int s0 = msrc[i], s1 = msrc[i + 1];
    float w0 = __expf(alr[(size_t)s0 * 8 + h] - mx);
    float w1 = __expf(alr[(size_t)s1 * 8 + h] - mx);
    ushort4 r0 = *(const ushort4*)(v + (size_t)s0 * DD + l * 4);
    ushort4 r1 = *(const ushort4*)(v + (size_t)s1 * DD + l * 4);
    den0 += w0; den1 += w1;
    a0 = fmaf(w0, bf2f(r0.x), a0); c0 = fmaf(w1, bf2f(r1.x), c0);
    a1 = fmaf(w0, bf2f(r0.y), a1); c1 = fmaf(w1, bf2f(r1.y), c1);
    a2 = fmaf(w0, bf2f(r0.z), a2); c2 = fmaf(w1, bf2f(r1.z), c2);
    a3 = fmaf(w0, bf2f(r0.w), a3); c3 = fmaf(w1, bf2f(r1.w), c3);
  }
  if (i < end){
    int s0 = msrc[i];
    float w0 = __expf(alr[(size_t)s0 * 8 + h] - mx);
    ushort4 r0 = *(const ushort4*)(v + (size_t)s0 * DD + l * 4);
    den0 += w0;
    a0 = fmaf(w0, bf2f(r0.x), a0);
    a1 = fmaf(w0, bf2f(r0.y), a1);
    a2 = fmaf(w0, bf2f(r0.z), a2);
    a3 = fmaf(w0, bf2f(r0.w), a3);
  }
  float id_ = 1.f / (den0 + den1);
  *(float4*)(att1 + (size_t)n * DD + l * 4) =
      make_float4((a0 + c0) * id_, (a1 + c1) * id_, (a2 + c2) * id_, (a3 + c3) * id_);
}

// ---------- final fused (MFMA, 64-row/512-thr/single-buffer): m2(att1)+att0 + m3 + bias ----------
__global__ __launch_bounds__(512, 4) void k_final(
    const float* att1,
    const u16* __restrict__ WT2a, const u16* __restrict__ WT2b,
    const u16* __restrict__ WT3a, const u16* __restrict__ WT3b,
    const float* __restrict__ m2b1, const float* __restrict__ m2b2,
    const float* __restrict__ m3b1, const float* __restrict__ m3b2,
    const float* __restrict__ n2g, const float* __restrict__ n2b,
    const float* __restrict__ n3g, const float* __restrict__ n3b,
    const float* __restrict__ bias_v, const Small* __restrict__ sm,
    float* out)
{
  __shared__ u16 s_a[64 * AS];   // 33.3 KB
  const int tid = threadIdx.x;
  const int t0  = blockIdx.x * 64;
  const int w = tid >> 6, lane = tid & 63;
  const int l15 = lane & 15, g = lane >> 4;
  const int cb = w * 32;

  f32x4 xr[8];
  {
    float4 gg = *(const float4*)(n2g + lane * 4);
    float4 bb = *(const float4*)(n2b + lane * 4);
    #pragma unroll
    for (int i = 0; i < 8; i++){
      int r = w * 8 + i;
      int t = t0 + r;
      float4 xv = make_float4(0.f, 0.f, 0.f, 0.f);
      if (t < N_NODES) xv = *(const float4*)(att1 + (size_t)t * DD + lane * 4);
      xr[i][0] = xv.x; xr[i][1] = xv.y; xr[i][2] = xv.z; xr[i][3] = xv.w;
      float s  = xv.x + xv.y + xv.z + xv.w;
      float ss = fmaf(xv.x, xv.x, fmaf(xv.y, xv.y, fmaf(xv.z, xv.z, xv.w * xv.w)));
      s = wredsum(s); ss = wredsum(ss);
      float mu  = s * (1.f / 256.f);
      float var = fmaf(-mu, mu, ss * (1.f / 256.f));
      float rs  = rsqrtf(var + 1e-5f);
      uint2 p2;
      p2.x = pkbf(fmaf((xv.x - mu) * rs, gg.x, bb.x), fmaf((xv.y - mu) * rs, gg.y, bb.y));
      p2.y = pkbf(fmaf((xv.z - mu) * rs, gg.z, bb.z), fmaf((xv.w - mu) * rs, gg.w, bb.w));
      *(uint2*)(s_a + r * AS + lane * 4) = p2;
    }
  }
  __syncthreads();

  f32x4 fr[4][2];
  mfma_tile64<false>(s_a, WT2a, nullptr, tid, fr, nullptr);
  __syncthreads();
  {
    float bc[2], pc[2];
    #pragma unroll
    for (int n = 0; n < 2; n++){
      int col = cb + n * 16 + l15;
      bc[n] = m2b1[col]; pc[n] = sm->pc2[1][col];
    }
    #pragma unroll
    for (int m = 0; m < 4; m++)
      #pragma unroll
      for (int n = 0; n < 2; n++){
        int col = cb + n * 16 + l15;
        #pragma unroll
        for (int r = 0; r < 4; r++){
          int row = m * 16 + 4 * g + r;
          s_a[row * AS + col] = f2bf(fmaxf(fr[m][n][r] + bc[n] + pc[n], 0.f));
        }
      }
  }
  __syncthreads();
  mfma_tile64<false>(s_a, WT2b, nullptr, tid, fr, nullptr);
  __syncthreads();
  {
    float bc[2], ac[2];
    #pragma unroll
    for (int n = 0; n < 2; n++){
      int col = cb + n * 16 + l15;
      bc[n] = m2b2[col]; ac[n] = sm->att0_upd[col];
    }
    #pragma unroll
    for (int m = 0; m < 4; m++)
      #pragma unroll
      for (int n = 0; n < 2; n++){
        int col = cb + n * 16 + l15;
        #pragma unroll
        for (int r = 0; r < 4; r++){
          int row = m * 16 + 4 * g + r;
          s_a[row * AS + col] = f2bf(fr[m][n][r] + bc[n] + ac[n]);
        }
      }
  }
  __syncthreads();
  {
    float4 gg = *(const float4*)(n3g + lane * 4);
    float4 bb = *(const float4*)(n3b + lane * 4);
    #pragma unroll
    for (int i = 0; i < 8; i++){
      int r = w * 8 + i;
      uint2 q = *(const uint2*)(s_a + r * AS + lane * 4);
      float x0 = xr[i][0] + bf2f((u16)(q.x & 0xffff));
      float x1 = xr[i][1] + bf2f((u16)(q.x >> 16));
      float x2 = xr[i][2] + bf2f((u16)(q.y & 0xffff));
      float x3 = xr[i][3] + bf2f((u16)(q.y >> 16));
      xr[i][0] = x0; xr[i][1] = x1; xr[i][2] = x2; xr[i][3] = x3;
      float s  = x0 + x1 + x2 + x3;
      float ss = fmaf(x0, x0, fmaf(x1, x1, fmaf(x2, x2, x3 * x3)));
      s = wredsum(s); ss = wredsum(ss);
      float mu  = s * (1.f / 256.f);
      float var = fmaf(-mu, mu, ss * (1.f / 256.f));
      float rs  = rsqrtf(var + 1e-5f);
      uint2 p2;
      p2.x = pkbf(fmaf((x0 - mu) * rs, gg.x, bb.x), fmaf((x1 - mu) * rs, gg.y, bb.y));
      p2.y = pkbf(fmaf((x2 - mu) * rs, gg.z, bb.z), fmaf((x3 - mu) * rs, gg.w, bb.w));
      *(uint2*)(s_a + r * AS + lane * 4) = p2;
    }
  }
  __syncthreads();
  mfma_tile64<false>(s_a, WT3a, nullptr, tid, fr, nullptr);
  __syncthreads();
  {
    float bc[2];
    #pragma unroll
    for (int n = 0; n < 2; n++) bc[n] = m3b1[cb + n * 16 + l15];
    #pragma unroll
    for (int m = 0; m < 4; m++)
      #pragma unroll
      for (int n = 0; n < 2; n++){
        int col = cb + n * 16 + l15;
        #pragma unroll
        for (int r = 0; r < 4; r++){
          int row = m * 16 + 4 * g + r;
          s_a[row * AS + col] = f2bf(fmaxf(fr[m][n][r] + bc[n], 0.f));
        }
      }
  }
  __syncthreads();
  mfma_tile64<false>(s_a, WT3b, nullptr, tid, fr, nullptr);
  __syncthreads();
  {
    float bc[2];
    #pragma unroll
    for (int n = 0; n < 2; n++){
      int col = cb + n * 16 + l15;
      bc[n] = m3b2[col] + bias_v[col];
    }
    #pragma unroll
    for (int m = 0; m < 4; m++)
      #pragma unroll
      for (int n = 0; n < 2; n++){
        int col = cb + n * 16 + l15;
        #pragma unroll
        for (int r = 0; r < 4; r++){
          int row = m * 16 + 4 * g + r;
          s_a[row * AS + col] = f2bf(fr[m][n][r] + bc[n]);
        }
      }
  }
  __syncthreads();
  #pragma unroll
  for (int i = 0; i < 8; i++){
    int r = w * 8 + i;
    int t = t0 + r;
    if (t < N_NODES){
      uint2 q = *(const uint2*)(s_a + r * AS + lane * 4);
      float4 o;
      o.x = xr[i][0] + bf2f((u16)(q.x & 0xffff));
      o.y = xr[i][1] + bf2f((u16)(q.x >> 16));
      o.z = xr[i][2] + bf2f((u16)(q.y & 0xffff));
      o.w = xr[i][3] + bf2f((u16)(q.y >> 16));
      *(float4*)(out + (size_t)t * DD + lane * 4) = o;
    }
  }
}

extern "C" void kernel_launch(void* const* d_in, const int* in_sizes, int n_in,
                              void* d_out, int out_size, void* d_ws, size_t ws_size,
                              hipStream_t stream)
{
  const float* x_v = (const float*)d_in[0];
  const float* x_e = (const float*)d_in[1];
  const int* edge_orders = (const int*)d_in[2];
  const int* edge_index  = (const int*)d_in[3];
  const float* q_w1 = (const float*)d_in[4],  *q_b1 = (const float*)d_in[5];
  const float* q_w2 = (const float*)d_in[6],  *q_b2 = (const float*)d_in[7];
  const float* k_w  = (const float*)d_in[8],  *k_b  = (const float*)d_in[9];
  const float* v_w  = (const float*)d_in[10], *v_b  = (const float*)d_in[11];
  const float* m1w1 = (const float*)d_in[12], *m1b1 = (const float*)d_in[13];
  const float* m1w2 = (const float*)d_in[14], *m1b2 = (const float*)d_in[15];
  const float* m2w1 = (const float*)d_in[16], *m2b1 = (const float*)d_in[17];
  const float* m2w2 = (const float*)d_in[18], *m2b2 = (const float*)d_in[19];
  const float* m3w1 = (const float*)d_in[20], *m3b1 = (const float*)d_in[21];
  const float* m3w2 = (const float*)d_in[22], *m3b2 = (const float*)d_in[23];
  const float* n1g = (const float*)d_in[24], *n1b = (const float*)d_in[25];
  const float* n2g = (const float*)d_in[26], *n2b = (const float*)d_in[27];
  const float* n3g = (const float*)d_in[28], *n3b = (const float*)d_in[29];
  const float* bias_v = (const float*)d_in[30];

  char* ws = (char*)d_ws;
  u16*   v      = (u16*)  (ws + WS_V);
  float* alr    = (float*)(ws + WS_ALR);
  int*   cnt    = (int*)  (ws + WS_CNT);
  int*   off    = (int*)  (ws + WS_OFF);
  int*   cur    = (int*)  (ws + WS_CUR);
  int*   msrc   = (int*)  (ws + WS_MSRC);
  Small* sm     = (Small*)(ws + WS_SMALL);
  u16*   wtb    = (u16*)  (ws + WS_WTS);
  float* part   = (float*)(ws + WS_PART);
  float* pden   = (float*)(ws + WS_PDEN);
  float* pmax   = (float*)(ws + WS_PMAX);
  const int* src = edge_index;
  const int* tgt = edge_index + M_MSG;
  float* att1 = (float*)d_out;
  float* out  = (float*)d_out;

  k_preq<<<1, 512, 0, stream>>>(q_w1, q_b1, q_w2, q_b2, k_b, sm, cnt);
  k_prep<<<244, 256, 0, stream>>>(k_w, m1w1, m2w1, sm,
                                  m1w1, m1w2, v_w, m2w1, m2w2, m3w1, m3w2, wtb);
  k_fused1<<<FUSED_BLKS + HIST_BLKS, 512, 0, stream>>>(x_v, x_e, edge_orders,
                                                  wtb + 0 * 65536, wtb + 1 * 65536, wtb + 2 * 65536,
                                                  m1b1, m1b2, n1g, n1b, v_b, sm, v, alr,
                                                  part, pden, pmax, tgt, cnt);
  k_scanbc<<<2, 1024, 0, stream>>>(cnt, off, cur, part, pden, pmax,
                                   m2w1, m2b1, m2w2, m2b2, n2g, n2b, sm);
  k_scatter<<<(M_MSG + 255) / 256, 256, 0, stream>>>(src, tgt, cur, msrc);
  k_att1<<<(N_NODES + 3) / 4, 256, 0, stream>>>(off, msrc, alr, v, att1);
  k_final<<<(N_NODES + 63) / 64, 512, 0, stream>>>(att1,
                                                   wtb + 3 * 65536, wtb + 4 * 65536,
                                                   wtb + 5 * 65536, wtb + 6 * 65536,
                                                   m2b1, m2b2, m3b1, m3b2,
                                                   n2g, n2b, n3g, n3b, bias_v, sm, out);
}

// Round 13
// 245.463 us; speedup vs baseline: 1.4139x; 1.4139x over previous
//
#include <hip/hip_runtime.h>
#include <hip/hip_bf16.h>

#define N_NODES 30000
#define N_EDGE  60000
#define T_TOK   90000
#define M_MSG   390000
#define DD      256
#define HH      8
#define AS      260   // bf16 LDS tile stride (520 B rows: conflict-free b64 frag reads)
#define FUSED_BLKS 1407  // ceil(90000/64)
#define HIST_BLKS  762   // ceil(390000/512)
#define SCAT_BLKS 1524   // ceil(390000/256)
#define RED_BLKS  176    // ceil(1407/8)
#define ATT1_BLKS 7500   // ceil(30000/4)

typedef unsigned short u16;
typedef unsigned int   u32;
typedef short s16x8 __attribute__((ext_vector_type(8)));
typedef float f32x4 __attribute__((ext_vector_type(4)));

// ---------- workspace layout (bytes) ----------
constexpr size_t WS_V     = 0;                                   // bf16 [T][256]
constexpr size_t WS_ALR   = WS_V    + (size_t)T_TOK * DD * 2;    // f32  [T][8]
constexpr size_t WS_CNT   = WS_ALR  + (size_t)T_TOK * HH * 4;    // int  [N]
constexpr size_t WS_OFF   = WS_CNT  + (size_t)N_NODES * 4;       // int  [N+1]
constexpr size_t WS_CUR   = WS_OFF  + (size_t)(N_NODES + 1) * 4; // int  [N]
constexpr size_t WS_MSRC  = WS_CUR  + (size_t)N_NODES * 4;       // int  [M]
constexpr size_t WS_SMALL = ((WS_MSRC + (size_t)M_MSG * 4) + 255) & ~(size_t)255;

struct Small {
  u16 wts[16][256];     // folded score weights bf16, FRAGMENT-LINEAR
  float b0[8], b1f[8];
  float q[2][256];      // q0/q1 vectors (post q-MLP)
  float pe_c1[11][256]; // pe1[order] @ m1_w1[256:512,:]
  float pc2[2][256];    // pe2[s] @ m2_w1[256:512,:]
  float gmaxv[8], ginv[8];
  float att0_vec[256];
  float att0_upd[256];
};
constexpr size_t WS_WTS  = (WS_SMALL + sizeof(Small) + 255) & ~(size_t)255;
constexpr size_t WS_PART = WS_WTS  + 7 * 65536 * 2;              // f32 [FUSED_BLKS][256]
constexpr size_t WS_PDEN = WS_PART + (size_t)FUSED_BLKS * 256 * 4; // f32 [FUSED_BLKS][8]
constexpr size_t WS_PMAX = WS_PDEN + (size_t)FUSED_BLKS * 8 * 4;   // f32 [FUSED_BLKS][8]

__device__ __forceinline__ float bf2f(u16 a){ return __uint_as_float(((u32)a) << 16); }
// gfx950 v_cvt_pk_bf16_f32: packs 2 f32 -> 2 bf16 (RNE) in one instruction (T12 recipe)
__device__ __forceinline__ u32 pkbf(float lo, float hi){
  u32 r;
  asm("v_cvt_pk_bf16_f32 %0, %1, %2" : "=v"(r) : "v"(lo), "v"(hi));
  return r;
}
__device__ __forceinline__ u16 f2bf(float f){ return (u16)pkbf(f, f); }
__device__ __forceinline__ float wredsum(float x){
  #pragma unroll
  for (int s = 32; s > 0; s >>= 1) x += __shfl_xor(x, s, 64);
  return x;
}
__device__ __forceinline__ float wredmax(float x){
  #pragma unroll
  for (int s = 32; s > 0; s >>= 1) x = fmaxf(x, __shfl_xor(x, s, 64));
  return x;
}

union U8 { s16x8 v; uint2 u2[2]; uint4 u4; };

// ---------- MFMA 64-row tile GEMM (8 waves, 512 thr): wave w -> cols w*32..w*32+31 ----------
template<bool SC>
__device__ __forceinline__ void mfma_tile64(const u16* sa, const u16* __restrict__ WT,
                                            const u16* __restrict__ wts, int tid,
                                            f32x4 fr[4][2], f32x4* fs)
{
  const int lane = tid & 63, w = tid >> 6;
  const int l15 = lane & 15, g = lane >> 4;
  const int slab = w >> 1, nt0 = (w & 1) * 2;
  #pragma unroll
  for (int m = 0; m < 4; m++)
    #pragma unroll
    for (int n = 0; n < 2; n++) fr[m][n] = (f32x4){0.f, 0.f, 0.f, 0.f};
  const u16* ap = sa + l15 * AS + 4 * g;
  const u16* bp = WT + (size_t)slab * 16384 + lane * 8;
  const bool do_s = SC && (w == 0);
  #pragma unroll 4
  for (int c = 0; c < 8; c++){
    const int k0 = c * 32;
    U8 a[4];
    #pragma unroll
    for (int m = 0; m < 4; m++){
      a[m].u2[0] = *(const uint2*)(ap + m * 16 * AS + k0);
      a[m].u2[1] = *(const uint2*)(ap + m * 16 * AS + k0 + 16);
    }
    U8 b[2];
    #pragma unroll
    for (int n = 0; n < 2; n++)
      b[n].u4 = *(const uint4*)(bp + (c * 4 + nt0 + n) * 512);
    #pragma unroll
    for (int n = 0; n < 2; n++)
      #pragma unroll
      for (int m = 0; m < 4; m++)
        fr[m][n] = __builtin_amdgcn_mfma_f32_16x16x32_bf16(a[m].v, b[n].v, fr[m][n], 0, 0, 0);
    if (do_s){
      U8 bs;
      bs.u4 = *(const uint4*)(wts + c * 512 + lane * 8);
      #pragma unroll
      for (int m = 0; m < 4; m++)
        fs[m] = __builtin_amdgcn_mfma_f32_16x16x32_bf16(a[m].v, bs.v, fs[m], 0, 0, 0);
    }
  }
}

// ---------- K0a: q MLP (1 block, 512 thr) -> sm->q, b0/b1f; zero cnt + att0_vec ----------
__global__ void k_preq(const float* __restrict__ qw1, const float* __restrict__ qb1,
                       const float* __restrict__ qw2, const float* __restrict__ qb2,
                       const float* __restrict__ kb, Small* sm, int* cnt)
{
  __shared__ float s_qin[2][128];
  __shared__ float s_h1[2][256];
  __shared__ float s_q[2][256];
  int tid = threadIdx.x;
  int p = tid >> 8, col = tid & 255;
  for (int i = tid; i < N_NODES; i += 512) cnt[i] = 0;
  if (tid < 256) sm->att0_vec[tid] = 0.f;
  if (tid < 128){
    int i = tid >> 1;
    float dv = expf((float)(2 * i) * (-9.210340371976184f / 128.f));
    if (tid & 1){ s_qin[0][tid] = 1.f; s_qin[1][tid] = cosf(dv); }
    else        { s_qin[0][tid] = 0.f; s_qin[1][tid] = sinf(dv); }
  }
  __syncthreads();
  {
    float acc = qb1[col];
    for (int d = 0; d < 128; d++) acc = fmaf(s_qin[p][d], qw1[d * 256 + col], acc);
    s_h1[p][col] = fmaxf(acc, 0.f);
  }
  __syncthreads();
  {
    float acc = qb2[col];
    for (int k = 0; k < 256; k++) acc = fmaf(s_h1[p][k], qw2[k * 256 + col], acc);
    s_q[p][col] = acc;
    sm->q[p][col] = acc;
  }
  __syncthreads();
  if (tid < 8){
    float b0 = 0.f, b1 = 0.f;
    for (int i = 0; i < 32; i++){
      b0 = fmaf(kb[tid * 32 + i],       s_q[0][tid * 32 + i], b0);
      b1 = fmaf(kb[256 + tid * 32 + i], s_q[1][tid * 32 + i], b1);
    }
    sm->b0[tid] = b0; sm->b1f[tid] = b1;
  }
}

// ---------- K0b: merged precompute — roles 0..19 = kw-fold/PE tables, 20..243 = wconv ----------
__global__ void k_prep(const float* __restrict__ kw, const float* __restrict__ m1w1,
                       const float* __restrict__ m2w1, Small* sm,
                       const float* __restrict__ s0, const float* __restrict__ s1,
                       const float* __restrict__ s2, const float* __restrict__ s3,
                       const float* __restrict__ s4, const float* __restrict__ s5,
                       const float* __restrict__ s6, u16* __restrict__ dst)
{
  int role = blockIdx.x, tid = threadIdx.x;
  if (role < 8){
    int d = role * 32 + (tid >> 3), h = tid & 7;
    float a0 = 0.f, a1 = 0.f;
    #pragma unroll
    for (int i = 0; i < 32; i++){
      a0 = fmaf(kw[d * 512 + h * 32 + i],       sm->q[0][h * 32 + i], a0);
      a1 = fmaf(kw[d * 512 + 256 + h * 32 + i], sm->q[1][h * 32 + i], a1);
    }
    int c = d >> 5, kk = d & 31;
    int g = (kk & 15) >> 2;
    int j = (kk & 3) + ((kk & 16) ? 4 : 0);
    u16* wf = &sm->wts[0][0];
    wf[(c * 64 + g * 16 + h) * 8 + j]     = f2bf(a0);
    wf[(c * 64 + g * 16 + 8 + h) * 8 + j] = f2bf(a1);
  } else if (role < 19){
    __shared__ float s_pe[256];
    int o = role - 8;
    {
      int i = tid >> 1;
      float dv = expf((float)(2 * i) * (-9.210340371976184f / 256.f));
      float ph = (float)o * dv;
      s_pe[tid] = (tid & 1) ? cosf(ph) : sinf(ph);
    }
    __syncthreads();
    float acc = 0.f;
    for (int d = 0; d < 256; d++) acc = fmaf(s_pe[d], m1w1[(256 + d) * 256 + tid], acc);
    sm->pe_c1[o][tid] = acc;
  } else if (role == 19){
    __shared__ float p0[256], p1[256];
    {
      int i = tid >> 1;
      float dv = expf((float)(2 * i) * (-9.210340371976184f / 256.f));
      p0[tid] = (tid & 1) ? 1.f : 0.f;
      p1[tid] = (tid & 1) ? cosf(dv) : sinf(dv);
    }
    __syncthreads();
    float a0 = 0.f, a1 = 0.f;
    for (int d = 0; d < 256; d++){
      float w = m2w1[(256 + d) * 256 + tid];
      a0 = fmaf(p0[d], w, a0);
      a1 = fmaf(p1[d], w, a1);
    }
    sm->pc2[0][tid] = a0; sm->pc2[1][tid] = a1;
  } else {
    int b = role - 20;             // 224 wconv tiles: 7 mats x 4 slabs x 8 chunks
    int mat = b >> 5, rem = b & 31;
    int slab = rem >> 3, c = rem & 7;
    const float* S;
    switch (mat){ case 0: S = s0; break; case 1: S = s1; break; case 2: S = s2; break;
                  case 3: S = s3; break; case 4: S = s4; break; case 5: S = s5; break;
                  default: S = s6; }
    int nt = tid >> 6, lane = tid & 63;
    int l15 = lane & 15, g = lane >> 4;
    int n = slab * 64 + nt * 16 + l15;
    u16 tmp[8];
    #pragma unroll
    for (int j = 0; j < 8; j++){
      int k = c * 32 + g * 4 + (j & 3) + ((j >= 4) ? 16 : 0);
      tmp[j] = f2bf(S[(size_t)k * 256 + n]);
    }
    uint4 o;
    o.x = (u32)tmp[0] | ((u32)tmp[1] << 16);
    o.y = (u32)tmp[2] | ((u32)tmp[3] << 16);
    o.z = (u32)tmp[4] | ((u32)tmp[5] << 16);
    o.w = (u32)tmp[6] | ((u32)tmp[7] << 16);
    *(uint4*)(dst + (size_t)mat * 65536 + (size_t)((((slab * 8 + c) * 4 + nt) * 64 + lane) * 8)) = o;
  }
}

// ---------- K1: FUSED phase-1 MLP + V proj + scores + att0 block-partials + hist roles ----------
__global__ __launch_bounds__(512, 4) void k_fused1(
    const float* __restrict__ x_v, const float* __restrict__ x_e,
    const int* __restrict__ edge_orders,
    const u16* __restrict__ WTa, const u16* __restrict__ WTb, const u16* __restrict__ WTv,
    const float* __restrict__ b1, const float* __restrict__ b2,
    const float* __restrict__ n1g, const float* __restrict__ n1b,
    const float* __restrict__ vb,
    const Small* __restrict__ sm,
    u16* __restrict__ v, float* __restrict__ alr,
    float* __restrict__ part, float* __restrict__ pden, float* __restrict__ pmax,
    const int* __restrict__ tgt, int* __restrict__ cnt)
{
  if (blockIdx.x >= FUSED_BLKS){
    int m = (blockIdx.x - FUSED_BLKS) * 512 + threadIdx.x;
    if (m < M_MSG) atomicAdd(&cnt[tgt[m]], 1);
    return;
  }
  __shared__ u16 s_a[64 * AS];   // 33.3 KB
  __shared__ int s_ord[64];
  __shared__ float s_l[64][8];   // logit tile (fake rows = -1e30)
  __shared__ float s_e[8][64];   // per-head exp weights
  __shared__ float s_p2[512];
  const int tid = threadIdx.x;
  const int t0  = blockIdx.x * 64;
  const int w = tid >> 6, lane = tid & 63;
  const int l15 = lane & 15, g = lane >> 4;
  const int cb = w * 32;

  // ---- load x + LN -> s_a; residual x kept packed bf16 in regs (fully unrolled: rule #20) ----
  uint2 xp[8];
  {
    float4 gg = *(const float4*)(n1g + lane * 4);
    float4 bb = *(const float4*)(n1b + lane * 4);
    #pragma unroll
    for (int i = 0; i < 8; i++){
      int r = w * 8 + i;
      int t = t0 + r;
      float4 xv = make_float4(0.f, 0.f, 0.f, 0.f);
      if (t < T_TOK){
        const float* p = (t < N_EDGE) ? (x_e + (size_t)t * DD) : (x_v + (size_t)(t - N_EDGE) * DD);
        xv = *(const float4*)(p + lane * 4);
      }
      xp[i].x = pkbf(xv.x, xv.y);
      xp[i].y = pkbf(xv.z, xv.w);
      float s  = xv.x + xv.y + xv.z + xv.w;
      float ss = fmaf(xv.x, xv.x, fmaf(xv.y, xv.y, fmaf(xv.z, xv.z, xv.w * xv.w)));
      s = wredsum(s); ss = wredsum(ss);
      float mu  = s * (1.f / 256.f);
      float var = fmaf(-mu, mu, ss * (1.f / 256.f));
      float rs  = rsqrtf(var + 1e-5f);
      uint2 p2;
      p2.x = pkbf(fmaf((xv.x - mu) * rs, gg.x, bb.x), fmaf((xv.y - mu) * rs, gg.y, bb.y));
      p2.y = pkbf(fmaf((xv.z - mu) * rs, gg.z, bb.z), fmaf((xv.w - mu) * rs, gg.w, bb.w));
      *(uint2*)(s_a + r * AS + lane * 4) = p2;
    }
  }
  if (tid < 64){
    int t = t0 + tid;
    s_ord[tid] = (t < N_EDGE) ? edge_orders[t] : 1;
  }
  __syncthreads();

  f32x4 fr[4][2];
  // ---- GEMM1: h1 = relu(LN(x) @ m1w1 + b1 + pe) ----
  mfma_tile64<false>(s_a, WTa, nullptr, tid, fr, nullptr);
  __syncthreads();
  {
    float b1c[2];
    #pragma unroll
    for (int n = 0; n < 2; n++) b1c[n] = b1[cb + n * 16 + l15];
    #pragma unroll
    for (int m = 0; m < 4; m++){
      #pragma unroll
      for (int r = 0; r < 4; r++){
        int row = m * 16 + 4 * g + r;
        const float* per = &sm->pe_c1[s_ord[row]][0];
        #pragma unroll
        for (int n = 0; n < 2; n++){
          int col = cb + n * 16 + l15;
          s_a[row * AS + col] = f2bf(fmaxf(fr[m][n][r] + b1c[n] + per[col], 0.f));
        }
      }
    }
  }
  __syncthreads();
  // ---- GEMM2: mlp = h1 @ m1w2 + b2 -> back into s_a ----
  mfma_tile64<false>(s_a, WTb, nullptr, tid, fr, nullptr);
  __syncthreads();
  {
    float b2c[2];
    #pragma unroll
    for (int n = 0; n < 2; n++) b2c[n] = b2[cb + n * 16 + l15];
    #pragma unroll
    for (int m = 0; m < 4; m++)
      #pragma unroll
      for (int n = 0; n < 2; n++){
        int col = cb + n * 16 + l15;
        #pragma unroll
        for (int r = 0; r < 4; r++){
          int row = m * 16 + 4 * g + r;
          s_a[row * AS + col] = f2bf(fr[m][n][r] + b2c[n]);
        }
      }
  }
  __syncthreads();
  // ---- tok = bf16(mlp + x): in-place RMW ----
  #pragma unroll
  for (int i = 0; i < 8; i++){
    int r = w * 8 + i;
    uint2 q = *(const uint2*)(s_a + r * AS + lane * 4);
    uint2 xq = xp[i];
    uint2 o;
    o.x = pkbf(bf2f((u16)(q.x & 0xffff)) + bf2f((u16)(xq.x & 0xffff)),
               bf2f((u16)(q.x >> 16))    + bf2f((u16)(xq.x >> 16)));
    o.y = pkbf(bf2f((u16)(q.y & 0xffff)) + bf2f((u16)(xq.y & 0xffff)),
               bf2f((u16)(q.y >> 16))    + bf2f((u16)(xq.y >> 16)));
    *(uint2*)(s_a + r * AS + lane * 4) = o;
  }
  __syncthreads();
  // ---- GEMM3: v = tok @ v_w + vb (+ score GEMM on wave 0) ----
  f32x4 fs[4];
  #pragma unroll
  for (int m = 0; m < 4; m++) fs[m] = (f32x4){0.f, 0.f, 0.f, 0.f};
  mfma_tile64<true>(s_a, WTv, &sm->wts[0][0], tid, fr, fs);
  __syncthreads();
  {
    float vbc[2];
    #pragma unroll
    for (int n = 0; n < 2; n++) vbc[n] = vb[cb + n * 16 + l15];
    #pragma unroll
    for (int m = 0; m < 4; m++)
      #pragma unroll
      for (int n = 0; n < 2; n++){
        int col = cb + n * 16 + l15;
        #pragma unroll
        for (int r = 0; r < 4; r++){
          int row = m * 16 + 4 * g + r;
          s_a[row * AS + col] = f2bf(fr[m][n][r] + vbc[n]);
        }
      }
  }
  if (w == 0){
    #pragma unroll
    for (int m = 0; m < 4; m++)
      #pragma unroll
      for (int r = 0; r < 4; r++){
        int row = m * 16 + 4 * g + r;
        int t = t0 + row;
        int sc = l15;
        if (sc < 8){
          float lv = (t < T_TOK) ? (fs[m][r] + sm->b0[sc]) * 0.17677669529663687f : -1e30f;
          s_l[row][sc] = lv;
        } else if (t < T_TOK){
          float a_ = fs[m][r] + sm->b1f[sc - 8];
          alr[(size_t)t * 8 + sc - 8] = (a_ > 0.f) ? a_ : 0.2f * a_;
        }
      }
  }
  __syncthreads();   // s_a = v-tile visible; s_l visible
  // ---- att0 block-partials: wave w = head w computes per-row exp weights ----
  {
    float lv = s_l[lane][w];
    float mxb = wredmax(lv);
    float e = __expf(lv - mxb);
    float den = wredsum(e);
    s_e[w][lane] = e;
    if (lane == 0){
      pden[(size_t)blockIdx.x * 8 + w] = den;
      pmax[(size_t)blockIdx.x * 8 + w] = mxb;
    }
  }
  __syncthreads();
  // ---- weighted V-sum: 2 threads/col x 32 rows each ----
  {
    int col = tid & 255, half = tid >> 8;
    int h = col >> 5;
    float acc = 0.f;
    #pragma unroll 8
    for (int r2 = half * 32; r2 < half * 32 + 32; r2++)
      acc = fmaf(s_e[h][r2], bf2f(s_a[r2 * AS + col]), acc);
    s_p2[tid] = acc;
  }
  __syncthreads();
  if (tid < 256) part[(size_t)blockIdx.x * 256 + tid] = s_p2[tid] + s_p2[tid + 256];
  // ---- stage v -> global (coalesced uint4) ----
  #pragma unroll
  for (int i = 0; i < 4; i++){
    int ch = i * 512 + tid;
    int r = ch >> 5, c8 = (ch & 31) * 8;
    int t = t0 + r;
    if (t < T_TOK){
      uint2 q0 = *(const uint2*)(s_a + r * AS + c8);
      uint2 q1 = *(const uint2*)(s_a + r * AS + c8 + 4);
      *(uint4*)(v + (size_t)t * DD + c8) = make_uint4(q0.x, q0.y, q1.x, q1.y);
    }
  }
}

// ---------- K2: block 0 = CSR scan; block 1 = att0 gmax + global denom ----------
__global__ __launch_bounds__(1024) void k_scanbc(
    const int* __restrict__ cnt, int* __restrict__ off, int* __restrict__ cur,
    const float* __restrict__ pden, const float* __restrict__ pmax,
    Small* sm)
{
  int tid = threadIdx.x;
  if (blockIdx.x == 0){
    __shared__ int s_s[1024];
    int base = tid * 30;
    int s = 0;
    if (tid < 1000){
      for (int i = 0; i < 30; i++) s += cnt[base + i];
    }
    s_s[tid] = s;
    __syncthreads();
    for (int ofs = 1; ofs < 1024; ofs <<= 1){
      int v_ = (tid >= ofs) ? s_s[tid - ofs] : 0;
      __syncthreads();
      s_s[tid] += v_;
      __syncthreads();
    }
    if (tid < 1000){
      int run = (tid == 0) ? 0 : s_s[tid - 1];
      for (int i = 0; i < 30; i++){
        int c = cnt[base + i];
        off[base + i] = run; cur[base + i] = run;
        run += c;
      }
    }
    if (tid == 0) off[N_NODES] = M_MSG;
    return;
  }
  // gmax + rescaled denom per head (1024 threads, 128 partial rows per thread-column)
  __shared__ float s_red[1024];
  __shared__ float s_g[8];
  {
    int h = tid & 7, bi = tid >> 3;      // bi in [0,128)
    float m = -1e30f;
    for (int b = bi; b < FUSED_BLKS; b += 128) m = fmaxf(m, pmax[(size_t)b * 8 + h]);
    s_red[tid] = m;
  }
  __syncthreads();
  for (int s = 512; s >= 8; s >>= 1){ if (tid < s) s_red[tid] = fmaxf(s_red[tid], s_red[tid + s]); __syncthreads(); }
  if (tid < 8) s_g[tid] = s_red[tid];
  __syncthreads();
  {
    int h = tid & 7, bi = tid >> 3;
    float gm = s_g[h];
    float s = 0.f;
    for (int b = bi; b < FUSED_BLKS; b += 128)
      s += pden[(size_t)b * 8 + h] * __expf(pmax[(size_t)b * 8 + h] - gm);
    s_red[tid] = s;
  }
  __syncthreads();
  for (int s = 512; s >= 8; s >>= 1){ if (tid < s) s_red[tid] += s_red[tid + s]; __syncthreads(); }
  if (tid < 8){ sm->gmaxv[tid] = s_g[tid]; sm->ginv[tid] = 1.f / s_red[tid]; }
}

// ---------- K3: CSR scatter + att0 partial-reduce role-blocks ----------
__global__ __launch_bounds__(256) void k_scatred(
    const int* __restrict__ src, const int* __restrict__ tgt,
    int* __restrict__ cur, int* __restrict__ msrc,
    const float* __restrict__ part, const float* __restrict__ pmax,
    Small* sm)
{
  int b = blockIdx.x, tid = threadIdx.x;
  if (b < SCAT_BLKS){
    int m = b * 256 + tid;
    if (m < M_MSG){
      int slot = atomicAdd(&cur[tgt[m]], 1);
      msrc[slot] = src[m];
    }
    return;
  }
  int r = b - SCAT_BLKS;
  int h = tid >> 5;
  float gm = sm->gmaxv[h];
  float acc = 0.f;
  #pragma unroll
  for (int j = 0; j < 8; j++){
    int pb = r * 8 + j;
    if (pb < FUSED_BLKS)
      acc = fmaf(part[(size_t)pb * 256 + tid], __expf(pmax[(size_t)pb * 8 + h] - gm), acc);
  }
  atomicAdd(&sm->att0_vec[tid], acc);
}

// ---------- segment softmax + weighted gather (att1) + att0-epilogue role block ----------
__global__ __launch_bounds__(256) void k_att1(
    const int* __restrict__ off, const int* __restrict__ msrc,
    const float* __restrict__ alr, const u16* __restrict__ v,
    const float* __restrict__ m2w1, const float* __restrict__ m2b1,
    const float* __restrict__ m2w2, const float* __restrict__ m2b2,
    const float* __restrict__ n2g, const float* __restrict__ n2b,
    Small* sm, float* att1)
{
  int tid = threadIdx.x;
  if (blockIdx.x == ATT1_BLKS){
    // ---- att0 epilogue: x = att0_vec*ginv -> LN -> m2 MLP -> att0_upd ----
    __shared__ float s_ln[256], s_h[256], s_r8[8];
    float x = sm->att0_vec[tid] * sm->ginv[tid >> 5];
    float s1 = wredsum(x), s2 = wredsum(x * x);
    int wv = tid >> 6;
    if ((tid & 63) == 0){ s_r8[wv] = s1; s_r8[4 + wv] = s2; }
    __syncthreads();
    float tot  = s_r8[0] + s_r8[1] + s_r8[2] + s_r8[3];
    float tot2 = s_r8[4] + s_r8[5] + s_r8[6] + s_r8[7];
    float mu  = tot * (1.f / 256.f);
    float var = tot2 * (1.f / 256.f) - mu * mu;
    float rs  = rsqrtf(var + 1e-5f);
    s_ln[tid] = (x - mu) * rs * n2g[tid] + n2b[tid];
    __syncthreads();
    float acc = m2b1[tid] + sm->pc2[0][tid];
    for (int k = 0; k < 256; k++) acc = fmaf(s_ln[k], m2w1[k * 256 + tid], acc);
    s_h[tid] = fmaxf(acc, 0.f);
    __syncthreads();
    float o = m2b2[tid];
    for (int k = 0; k < 256; k++) o = fmaf(s_h[k], m2w2[k * 256 + tid], o);
    sm->att0_upd[tid] = x + o;
    return;
  }
  int n = blockIdx.x * 4 + (tid >> 6);
  if (n >= N_NODES) return;
  int l = tid & 63;
  int h = l >> 3;
  int beg = off[n], end = off[n + 1];
  float mxa = -1e30f, mxb = -1e30f;
  int i = beg;
  for (; i + 1 < end; i += 2){
    mxa = fmaxf(mxa, alr[(size_t)msrc[i] * 8 + h]);
    mxb = fmaxf(mxb, alr[(size_t)msrc[i + 1] * 8 + h]);
  }
  if (i < end) mxa = fmaxf(mxa, alr[(size_t)msrc[i] * 8 + h]);
  float mx = fmaxf(mxa, mxb);
  float den0 = 0.f, den1 = 0.f;
  float a0 = 0.f, a1 = 0.f, a2 = 0.f, a3 = 0.f;
  float c0 = 0.f, c1 = 0.f, c2 = 0.f, c3 = 0.f;
  i = beg;
  for (; i + 1 < end; i += 2){
    int s0 = msrc[i], s1 = msrc[i + 1];
    float w0 = __expf(alr[(size_t)s0 * 8 + h] - mx);
    float w1 = __expf(alr[(size_t)s1 * 8 + h] - mx);
    ushort4 r0 = *(const ushort4*)(v + (size_t)s0 * DD + l * 4);
    ushort4 r1 = *(const ushort4*)(v + (size_t)s1 * DD + l * 4);
    den0 += w0; den1 += w1;
    a0 = fmaf(w0, bf2f(r0.x), a0); c0 = fmaf(w1, bf2f(r1.x), c0);
    a1 = fmaf(w0, bf2f(r0.y), a1); c1 = fmaf(w1, bf2f(r1.y), c1);
    a2 = fmaf(w0, bf2f(r0.z), a2); c2 = fmaf(w1, bf2f(r1.z), c2);
    a3 = fmaf(w0, bf2f(r0.w), a3); c3 = fmaf(w1, bf2f(r1.w), c3);
  }
  if (i < end){
    int s0 = msrc[i];
    float w0 = __expf(alr[(size_t)s0 * 8 + h] - mx);
    ushort4 r0 = *(const ushort4*)(v + (size_t)s0 * DD + l * 4);
    den0 += w0;
    a0 = fmaf(w0, bf2f(r0.x), a0);
    a1 = fmaf(w0, bf2f(r0.y), a1);
    a2 = fmaf(w0, bf2f(r0.z), a2);
    a3 = fmaf(w0, bf2f(r0.w), a3);
  }
  float id_ = 1.f / (den0 + den1);
  *(float4*)(att1 + (size_t)n * DD + l * 4) =
      make_float4((a0 + c0) * id_, (a1 + c1) * id_, (a2 + c2) * id_, (a3 + c3) * id_);
}

// ---------- final fused (MFMA, 64-row/512-thr/single-buffer): m2(att1)+att0 + m3 + bias ----------
__global__ __launch_bounds__(512, 4) void k_final(
    const float* att1,
    const u16* __restrict__ WT2a, const u16* __restrict__ WT2b,
    const u16* __restrict__ WT3a, const u16* __restrict__ WT3b,
    const float* __restrict__ m2b1, const float* __restrict__ m2b2,
    const float* __restrict__ m3b1, const float* __restrict__ m3b2,
    const float* __restrict__ n2g, const float* __restrict__ n2b,
    const float* __restrict__ n3g, const float* __restrict__ n3b,
    const float* __restrict__ bias_v, const Small* __restrict__ sm,
    float* out)
{
  __shared__ u16 s_a[64 * AS];   // 33.3 KB
  const int tid = threadIdx.x;
  const int t0  = blockIdx.x * 64;
  const int w = tid >> 6, lane = tid & 63;
  const int l15 = lane & 15, g = lane >> 4;
  const int cb = w * 32;

  f32x4 xr[8];
  {
    float4 gg = *(const float4*)(n2g + lane * 4);
    float4 bb = *(const float4*)(n2b + lane * 4);
    #pragma unroll
    for (int i = 0; i < 8; i++){
      int r = w * 8 + i;
      int t = t0 + r;
      float4 xv = make_float4(0.f, 0.f, 0.f, 0.f);
      if (t < N_NODES) xv = *(const float4*)(att1 + (size_t)t * DD + lane * 4);
      xr[i][0] = xv.x; xr[i][1] = xv.y; xr[i][2] = xv.z; xr[i][3] = xv.w;
      float s  = xv.x + xv.y + xv.z + xv.w;
      float ss = fmaf(xv.x, xv.x, fmaf(xv.y, xv.y, fmaf(xv.z, xv.z, xv.w * xv.w)));
      s = wredsum(s); ss = wredsum(ss);
      float mu  = s * (1.f / 256.f);
      float var = fmaf(-mu, mu, ss * (1.f / 256.f));
      float rs  = rsqrtf(var + 1e-5f);
      uint2 p2;
      p2.x = pkbf(fmaf((xv.x - mu) * rs, gg.x, bb.x), fmaf((xv.y - mu) * rs, gg.y, bb.y));
      p2.y = pkbf(fmaf((xv.z - mu) * rs, gg.z, bb.z), fmaf((xv.w - mu) * rs, gg.w, bb.w));
      *(uint2*)(s_a + r * AS + lane * 4) = p2;
    }
  }
  __syncthreads();

  f32x4 fr[4][2];
  mfma_tile64<false>(s_a, WT2a, nullptr, tid, fr, nullptr);
  __syncthreads();
  {
    float bc[2], pc[2];
    #pragma unroll
    for (int n = 0; n < 2; n++){
      int col = cb + n * 16 + l15;
      bc[n] = m2b1[col]; pc[n] = sm->pc2[1][col];
    }
    #pragma unroll
    for (int m = 0; m < 4; m++)
      #pragma unroll
      for (int n = 0; n < 2; n++){
        int col = cb + n * 16 + l15;
        #pragma unroll
        for (int r = 0; r < 4; r++){
          int row = m * 16 + 4 * g + r;
          s_a[row * AS + col] = f2bf(fmaxf(fr[m][n][r] + bc[n] + pc[n], 0.f));
        }
      }
  }
  __syncthreads();
  mfma_tile64<false>(s_a, WT2b, nullptr, tid, fr, nullptr);
  __syncthreads();
  {
    float bc[2], ac[2];
    #pragma unroll
    for (int n = 0; n < 2; n++){
      int col = cb + n * 16 + l15;
      bc[n] = m2b2[col]; ac[n] = sm->att0_upd[col];
    }
    #pragma unroll
    for (int m = 0; m < 4; m++)
      #pragma unroll
      for (int n = 0; n < 2; n++){
        int col = cb + n * 16 + l15;
        #pragma unroll
        for (int r = 0; r < 4; r++){
          int row = m * 16 + 4 * g + r;
          s_a[row * AS + col] = f2bf(fr[m][n][r] + bc[n] + ac[n]);
        }
      }
  }
  __syncthreads();
  {
    float4 gg = *(const float4*)(n3g + lane * 4);
    float4 bb = *(const float4*)(n3b + lane * 4);
    #pragma unroll
    for (int i = 0; i < 8; i++){
      int r = w * 8 + i;
      uint2 q = *(const uint2*)(s_a + r * AS + lane * 4);
      float x0 = xr[i][0] + bf2f((u16)(q.x & 0xffff));
      float x1 = xr[i][1] + bf2f((u16)(q.x >> 16));
      float x2 = xr[i][2] + bf2f((u16)(q.y & 0xffff));
      float x3 = xr[i][3] + bf2f((u16)(q.y >> 16));
      xr[i][0] = x0; xr[i][1] = x1; xr[i][2] = x2; xr[i][3] = x3;
      float s  = x0 + x1 + x2 + x3;
      float ss = fmaf(x0, x0, fmaf(x1, x1, fmaf(x2, x2, x3 * x3)));
      s = wredsum(s); ss = wredsum(ss);
      float mu  = s * (1.f / 256.f);
      float var = fmaf(-mu, mu, ss * (1.f / 256.f));
      float rs  = rsqrtf(var + 1e-5f);
      uint2 p2;
      p2.x = pkbf(fmaf((x0 - mu) * rs, gg.x, bb.x), fmaf((x1 - mu) * rs, gg.y, bb.y));
      p2.y = pkbf(fmaf((x2 - mu) * rs, gg.z, bb.z), fmaf((x3 - mu) * rs, gg.w, bb.w));
      *(uint2*)(s_a + r * AS + lane * 4) = p2;
    }
  }
  __syncthreads();
  mfma_tile64<false>(s_a, WT3a, nullptr, tid, fr, nullptr);
  __syncthreads();
  {
    float bc[2];
    #pragma unroll
    for (int n = 0; n < 2; n++) bc[n] = m3b1[cb + n * 16 + l15];
    #pragma unroll
    for (int m = 0; m < 4; m++)
      #pragma unroll
      for (int n = 0; n < 2; n++){
        int col = cb + n * 16 + l15;
        #pragma unroll
        for (int r = 0; r < 4; r++){
          int row = m * 16 + 4 * g + r;
          s_a[row * AS + col] = f2bf(fmaxf(fr[m][n][r] + bc[n], 0.f));
        }
      }
  }
  __syncthreads();
  mfma_tile64<false>(s_a, WT3b, nullptr, tid, fr, nullptr);
  __syncthreads();
  {
    float bc[2];
    #pragma unroll
    for (int n = 0; n < 2; n++){
      int col = cb + n * 16 + l15;
      bc[n] = m3b2[col] + bias_v[col];
    }
    #pragma unroll
    for (int m = 0; m < 4; m++)
      #pragma unroll
      for (int n = 0; n < 2; n++){
        int col = cb + n * 16 + l15;
        #pragma unroll
        for (int r = 0; r < 4; r++){
          int row = m * 16 + 4 * g + r;
          s_a[row * AS + col] = f2bf(fr[m][n][r] + bc[n]);
        }
      }
  }
  __syncthreads();
  #pragma unroll
  for (int i = 0; i < 8; i++){
    int r = w * 8 + i;
    int t = t0 + r;
    if (t < N_NODES){
      uint2 q = *(const uint2*)(s_a + r * AS + lane * 4);
      float4 o;
      o.x = xr[i][0] + bf2f((u16)(q.x & 0xffff));
      o.y = xr[i][1] + bf2f((u16)(q.x >> 16));
      o.z = xr[i][2] + bf2f((u16)(q.y & 0xffff));
      o.w = xr[i][3] + bf2f((u16)(q.y >> 16));
      *(float4*)(out + (size_t)t * DD + lane * 4) = o;
    }
  }
}

extern "C" void kernel_launch(void* const* d_in, const int* in_sizes, int n_in,
                              void* d_out, int out_size, void* d_ws, size_t ws_size,
                              hipStream_t stream)
{
  const float* x_v = (const float*)d_in[0];
  const float* x_e = (const float*)d_in[1];
  const int* edge_orders = (const int*)d_in[2];
  const int* edge_index  = (const int*)d_in[3];
  const float* q_w1 = (const float*)d_in[4],  *q_b1 = (const float*)d_in[5];
  const float* q_w2 = (const float*)d_in[6],  *q_b2 = (const float*)d_in[7];
  const float* k_w  = (const float*)d_in[8],  *k_b  = (const float*)d_in[9];
  const float* v_w  = (const float*)d_in[10], *v_b  = (const float*)d_in[11];
  const float* m1w1 = (const float*)d_in[12], *m1b1 = (const float*)d_in[13];
  const float* m1w2 = (const float*)d_in[14], *m1b2 = (const float*)d_in[15];
  const float* m2w1 = (const float*)d_in[16], *m2b1 = (const float*)d_in[17];
  const float* m2w2 = (const float*)d_in[18], *m2b2 = (const float*)d_in[19];
  const float* m3w1 = (const float*)d_in[20], *m3b1 = (const float*)d_in[21];
  const float* m3w2 = (const float*)d_in[22], *m3b2 = (const float*)d_in[23];
  const float* n1g = (const float*)d_in[24], *n1b = (const float*)d_in[25];
  const float* n2g = (const float*)d_in[26], *n2b = (const float*)d_in[27];
  const float* n3g = (const float*)d_in[28], *n3b = (const float*)d_in[29];
  const float* bias_v = (const float*)d_in[30];

  char* ws = (char*)d_ws;
  u16*   v      = (u16*)  (ws + WS_V);
  float* alr    = (float*)(ws + WS_ALR);
  int*   cnt    = (int*)  (ws + WS_CNT);
  int*   off    = (int*)  (ws + WS_OFF);
  int*   cur    = (int*)  (ws + WS_CUR);
  int*   msrc   = (int*)  (ws + WS_MSRC);
  Small* sm     = (Small*)(ws + WS_SMALL);
  u16*   wtb    = (u16*)  (ws + WS_WTS);
  float* part   = (float*)(ws + WS_PART);
  float* pden   = (float*)(ws + WS_PDEN);
  float* pmax   = (float*)(ws + WS_PMAX);
  const int* src = edge_index;
  const int* tgt = edge_index + M_MSG;
  float* att1 = (float*)d_out;
  float* out  = (float*)d_out;

  k_preq<<<1, 512, 0, stream>>>(q_w1, q_b1, q_w2, q_b2, k_b, sm, cnt);
  k_prep<<<244, 256, 0, stream>>>(k_w, m1w1, m2w1, sm,
                                  m1w1, m1w2, v_w, m2w1, m2w2, m3w1, m3w2, wtb);
  k_fused1<<<FUSED_BLKS + HIST_BLKS, 512, 0, stream>>>(x_v, x_e, edge_orders,
                                                  wtb + 0 * 65536, wtb + 1 * 65536, wtb + 2 * 65536,
                                                  m1b1, m1b2, n1g, n1b, v_b, sm, v, alr,
                                                  part, pden, pmax, tgt, cnt);
  k_scanbc<<<2, 1024, 0, stream>>>(cnt, off, cur, pden, pmax, sm);
  k_scatred<<<SCAT_BLKS + RED_BLKS, 256, 0, stream>>>(src, tgt, cur, msrc, part, pmax, sm);
  k_att1<<<ATT1_BLKS + 1, 256, 0, stream>>>(off, msrc, alr, v,
                                            m2w1, m2b1, m2w2, m2b2, n2g, n2b, sm, att1);
  k_final<<<(N_NODES + 63) / 64, 512, 0, stream>>>(att1,
                                                   wtb + 3 * 65536, wtb + 4 * 65536,
                                                   wtb + 5 * 65536, wtb + 6 * 65536,
                                                   m2b1, m2b2, m3b1, m3b2,
                                                   n2g, n2b, n3g, n3b, bias_v, sm, out);
}